// Round 8
// baseline (65.575 us; speedup 1.0000x reference)
//
#include <hip/hip_runtime.h>
#include <hip/hip_bf16.h>
#include <hip/hip_cooperative_groups.h>

namespace cg = cooperative_groups;

#define N_B   4
#define T_LEN 1024
#define NREF  128
#define H     4
#define KQ    128
#define LD    128
#define HKQ   512
#define HLD   512

typedef __attribute__((ext_vector_type(8))) short bf16x8;   // 8 bf16 = 4 VGPRs
typedef __attribute__((ext_vector_type(4))) float f32x4;

union V8 { __hip_bfloat16 h[8]; bf16x8 v; };
union V4 { __hip_bfloat16 h[4]; ushort4 u; };

__device__ __forceinline__ void sincos_pair(float t, int i, float* s, float* c) {
    // freq i in [0,32): angle = 48*t*exp(-2i*ln(10)/64)
    float div = __expf(-(float)(2 * i) * (2.302585093f / 64.0f));
    __sincosf(48.0f * t * div, s, c);
}

// Single cooperative kernel. grid 128 blocks x 512 threads.
// Phase 1 (job = blockIdx.x):
//   jobs 0..3    : A-tensor, full head h=job: hq = qin@Wq_h + bq (MFMA),
//                  A_h = hq @ Wk_h^T (MFMA, Wk_h staged in LDS). 128 q-rows, 8 waves.
//   jobs 4..35   : k_in build, 128 rows each -> kin bf16 [4096][128]
//   jobs 36..99  : xT transpose x[b,t,v] f32 -> xT[b,v,t] bf16 (64 t-rows each)
//   jobs 100..107: WoT transpose Wo[512][128] f32 -> WoT[128][512] bf16 (64 i-rows each)
//   jobs 108..111: out init: out[b][q][j] = bo[j]
//   jobs 112..127: idle
// grid.sync()
// Phase 2 (blk = qt + 8*h + 32*b): attention + partial projection for (16q, h, b):
//   8 waves; wave w scores keys [w*128,(w+1)*128) (32 MFMA), exact two-pass softmax
//   via one cross-wave LDS reduction, exp -> P_lds bf16 (swizzled), PV over all 1024
//   keys for v = w*16+lm (32 MFMA), normalize -> att_lds, partial proj (4 MFMA)
//   atomicAdd'ed into out (pre-init = bo).
__global__ __launch_bounds__(512) void fused_all(
    const float* __restrict__ ts, const int* __restrict__ ys0, const int* __restrict__ ys1,
    const float* __restrict__ x,
    const float* __restrict__ emb0, const float* __restrict__ emb1,
    const float* __restrict__ Wq, const float* __restrict__ bq,
    const float* __restrict__ Wk, const float* __restrict__ Wo,
    const float* __restrict__ bo,
    __hip_bfloat16* __restrict__ A, __hip_bfloat16* __restrict__ kin,
    __hip_bfloat16* __restrict__ xT, __hip_bfloat16* __restrict__ WoT,
    float* __restrict__ out)
{
    __shared__ __align__(16) unsigned char smem[65536];
    int tid = threadIdx.x;
    int job = blockIdx.x;
    const float scale = 0.08838834764831845f;  // 1/sqrt(128)

    // ================= PHASE 1 =================
    if (job < 4) {
        // ---------------- A job: full head h ----------------
        __hip_bfloat16* buf0 = (__hip_bfloat16*)smem;            // 128*128 bf16 = 32 KB (qin -> hq)
        __hip_bfloat16* wlds = (__hip_bfloat16*)(smem + 32768);  // 128*128 bf16 = 32 KB (WqT, then Wk_h)
        int h = job;

        // build qin (128 q rows x 128) bf16, XOR-swizzled rows
        for (int u = 0; u < 4; ++u) {
            int slot = u * 512 + tid;      // 0..2047
            int q = slot >> 4;             // 0..127
            int c0 = (slot & 15) * 8;
            V8 v;
            if (c0 < 64) {
                float t = (float)q / 127.0f;   // linspace(0,1,128)
                #pragma unroll
                for (int jj = 0; jj < 8; jj += 2) {
                    float s, c;
                    sincos_pair(t, (c0 + jj) >> 1, &s, &c);
                    v.h[jj] = __float2bfloat16(s);
                    v.h[jj + 1] = __float2bfloat16(c);
                }
            } else if (c0 < 96) {
                #pragma unroll
                for (int jj = 0; jj < 8; ++jj) v.h[jj] = __float2bfloat16(emb0[100 * 32 + (c0 - 64) + jj]);
            } else {
                #pragma unroll
                for (int jj = 0; jj < 8; ++jj) v.h[jj] = __float2bfloat16(emb1[50 * 32 + (c0 - 96) + jj]);
            }
            int idx = (q * 128 + c0) ^ ((q & 7) << 3);
            *(bf16x8*)&buf0[idx] = v.v;
        }
        // build WqT[d][i] bf16, swizzled (transpose of Wq_h); coalesced row reads
        for (int u = 0; u < 8; ++u) {
            int s = u * 512 + tid;         // 0..4095
            int i = s >> 5;                // 0..127
            int d0 = (s & 31) * 4;
            float4 w = *(const float4*)&Wq[(size_t)i * HKQ + h * KQ + d0];
            float wv[4] = {w.x, w.y, w.z, w.w};
            #pragma unroll
            for (int jj = 0; jj < 4; ++jj) {
                int d = d0 + jj;
                wlds[(d * 128 + i) ^ ((d & 7) << 3)] = __float2bfloat16(wv[jj]);
            }
        }
        __syncthreads();

        int wave = tid >> 6, lane = tid & 63, lm = lane & 15, lg = lane >> 4;
        // stage 1: hq[128q x 128d] = qin @ WqT + bq; wave owns 16 q rows
        f32x4 acc[8];
        #pragma unroll
        for (int dt = 0; dt < 8; ++dt) acc[dt] = f32x4{0.f, 0.f, 0.f, 0.f};
        #pragma unroll
        for (int ks = 0; ks < 4; ++ks) {
            int q = wave * 16 + lm;
            bf16x8 af = *(bf16x8*)&buf0[(q * 128 + ks * 32 + 8 * lg) ^ ((q & 7) << 3)];
            #pragma unroll
            for (int dt = 0; dt < 8; ++dt) {
                int d = dt * 16 + lm;
                bf16x8 bfr = *(bf16x8*)&wlds[(d * 128 + ks * 32 + 8 * lg) ^ ((d & 7) << 3)];
                acc[dt] = __builtin_amdgcn_mfma_f32_16x16x32_bf16(af, bfr, acc[dt], 0, 0, 0);
            }
        }
        __syncthreads();   // qin + WqT fully consumed
        // hq (+bias) -> buf0, swizzled
        #pragma unroll
        for (int dt = 0; dt < 8; ++dt) {
            int d = dt * 16 + lm;
            float bb = bq[h * KQ + d];
            #pragma unroll
            for (int r = 0; r < 4; ++r) {
                int q = wave * 16 + 4 * lg + r;
                buf0[(q * 128 + d) ^ ((q & 7) << 3)] = __float2bfloat16(acc[dt][r] + bb);
            }
        }
        // stage Wk_h rows (row-major, swizzled) into wlds; coalesced reads
        for (int u = 0; u < 8; ++u) {
            int s = u * 512 + tid;         // 0..4095
            int i = s >> 5;                // 0..127
            int d0 = (s & 31) * 4;
            float4 w = *(const float4*)&Wk[(size_t)i * HKQ + h * KQ + d0];
            V4 bv;
            bv.h[0] = __float2bfloat16(w.x); bv.h[1] = __float2bfloat16(w.y);
            bv.h[2] = __float2bfloat16(w.z); bv.h[3] = __float2bfloat16(w.w);
            *(ushort4*)&wlds[(i * 128 + d0) ^ ((i & 7) << 3)] = bv.u;
        }
        __syncthreads();
        // stage 2: A[128q x 128i] = hq @ Wk_h^T (contract d); B rows from LDS
        f32x4 acc2[8];
        #pragma unroll
        for (int it = 0; it < 8; ++it) acc2[it] = f32x4{0.f, 0.f, 0.f, 0.f};
        #pragma unroll
        for (int ks = 0; ks < 4; ++ks) {
            int q = wave * 16 + lm;
            bf16x8 af = *(bf16x8*)&buf0[(q * 128 + ks * 32 + 8 * lg) ^ ((q & 7) << 3)];
            #pragma unroll
            for (int it = 0; it < 8; ++it) {
                int i2 = it * 16 + lm;
                bf16x8 bv = *(bf16x8*)&wlds[(i2 * 128 + ks * 32 + 8 * lg) ^ ((i2 & 7) << 3)];
                acc2[it] = __builtin_amdgcn_mfma_f32_16x16x32_bf16(af, bv, acc2[it], 0, 0, 0);
            }
        }
        // store A: [h][q][i] bf16 (plain row-major)
        #pragma unroll
        for (int it = 0; it < 8; ++it) {
            int i2 = it * 16 + lm;
            #pragma unroll
            for (int r = 0; r < 4; ++r) {
                int q = wave * 16 + 4 * lg + r;
                A[((size_t)h * NREF + q) * KQ + i2] = __float2bfloat16(acc2[it][r]);
            }
        }
    } else if (job < 36) {
        // ---------------- k_in job: 128 rows ----------------
        int row0 = (job - 4) * 128;
        for (int u = 0; u < 4; ++u) {
            int slot = u * 512 + tid;     // 0..2047
            int r = slot >> 4;            // 0..127
            int c0 = (slot & 15) * 8;
            int bt = row0 + r;
            V8 v;
            if (c0 < 64) {
                float t = ts[bt];
                #pragma unroll
                for (int jj = 0; jj < 8; jj += 2) {
                    float s, c;
                    sincos_pair(t, (c0 + jj) >> 1, &s, &c);
                    v.h[jj] = __float2bfloat16(s);
                    v.h[jj + 1] = __float2bfloat16(c);
                }
            } else if (c0 < 96) {
                int y = ys0[bt];
                #pragma unroll
                for (int jj = 0; jj < 8; ++jj) v.h[jj] = __float2bfloat16(emb0[y * 32 + (c0 - 64) + jj]);
            } else {
                int y = ys1[bt];
                #pragma unroll
                for (int jj = 0; jj < 8; ++jj) v.h[jj] = __float2bfloat16(emb1[y * 32 + (c0 - 96) + jj]);
            }
            *(bf16x8*)&kin[(size_t)bt * KQ + c0] = v.v;
        }
    } else if (job < 100) {
        // ---------------- xT job: 64 t-rows ----------------
        __hip_bfloat16 (*tile)[136] = (__hip_bfloat16(*)[136])smem;   // 64*136*2 = 17.4 KB
        int jb = job - 36;
        int b = jb >> 4, t0 = (jb & 15) * 64;
        for (int u = 0; u < 4; ++u) {
            int e = u * 512 + tid;        // 0..2047
            int tt = e >> 5, v4 = e & 31;
            float4 xv = *(const float4*)&x[((size_t)(b * T_LEN + t0 + tt)) * LD + v4 * 4];
            tile[tt][v4 * 4 + 0] = __float2bfloat16(xv.x);
            tile[tt][v4 * 4 + 1] = __float2bfloat16(xv.y);
            tile[tt][v4 * 4 + 2] = __float2bfloat16(xv.z);
            tile[tt][v4 * 4 + 3] = __float2bfloat16(xv.w);
        }
        __syncthreads();
        int v = tid >> 2, th = (tid & 3) * 16;
        for (int i = 0; i < 16; i += 4) {
            ushort4 u;
            u.x = *(unsigned short*)&tile[th + i + 0][v];
            u.y = *(unsigned short*)&tile[th + i + 1][v];
            u.z = *(unsigned short*)&tile[th + i + 2][v];
            u.w = *(unsigned short*)&tile[th + i + 3][v];
            *(ushort4*)&xT[((size_t)b * LD + v) * T_LEN + t0 + th + i] = u;
        }
    } else if (job < 108) {
        // ---------------- WoT job: Wo[i][j] f32 -> WoT[j][i] bf16, 64-row i slab ----------------
        __hip_bfloat16 (*tile)[130] = (__hip_bfloat16(*)[130])smem;   // 64*130*2 = 16.6 KB
        int i0 = (job - 100) * 64;
        for (int u = 0; u < 16; ++u) {
            int e = u * 512 + tid;            // 0..8191
            int il = e >> 7, j = e & 127;
            tile[il][j] = __float2bfloat16(Wo[(size_t)(i0 + il) * LD + j]);
        }
        __syncthreads();
        for (int u = 0; u < 16; ++u) {
            int s = u * 512 + tid;            // 0..8191
            int j = s >> 6, il = s & 63;
            WoT[(size_t)j * HLD + i0 + il] = tile[il][j];
        }
    } else if (job < 112) {
        // ---------------- out init: out[b][q][j] = bo[j] ----------------
        int b = job - 108;
        for (int e = tid; e < NREF * LD; e += 512)
            out[(size_t)b * NREF * LD + e] = bo[e & 127];
    }
    // jobs 112..127: nothing

    cg::this_grid().sync();

    // ================= PHASE 2 =================
    // blk -> (qt, h, b)
    {
        __hip_bfloat16* P_lds   = (__hip_bfloat16*)smem;            // 16*1024 bf16 = 32 KB
        __hip_bfloat16* att_lds = (__hip_bfloat16*)(smem + 32768);  // 16*128 bf16 = 4 KB
        float* redm = (float*)(smem + 36864);                       // [8][16]
        float* reds = (float*)(smem + 37376);                       // [8][16]

        int w = tid >> 6, lane = tid & 63;
        int lm = lane & 15, lg = lane >> 4;
        int blk = blockIdx.x;
        int qt = blk & 7, h = (blk >> 3) & 3, b = blk >> 5;
        int q0 = qt * 16;

        // A-frags for the 16 q rows
        bf16x8 af[4];
        #pragma unroll
        for (int ks = 0; ks < 4; ++ks)
            af[ks] = *(const bf16x8*)(A + ((size_t)h * NREF + q0 + lm) * KQ + ks * 32 + lg * 8);

        // ---- scores for this wave's 128 keys: D[q=4lg+r][key = w*128 + kt*16 + lm]
        f32x4 sacc[8];
        #pragma unroll
        for (int kt = 0; kt < 8; ++kt) sacc[kt] = f32x4{0.f, 0.f, 0.f, 0.f};
        #pragma unroll
        for (int ks = 0; ks < 4; ++ks) {
            #pragma unroll
            for (int kt = 0; kt < 8; ++kt) {
                bf16x8 bfr = *(const bf16x8*)(kin + (size_t)(b * T_LEN + w * 128 + kt * 16 + lm) * KQ + ks * 32 + lg * 8);
                sacc[kt] = __builtin_amdgcn_mfma_f32_16x16x32_bf16(af[ks], bfr, sacc[kt], 0, 0, 0);
            }
        }
        // ---- per-wave row max -> LDS
        #pragma unroll
        for (int r = 0; r < 4; ++r) {
            float cm = sacc[0][r];
            #pragma unroll
            for (int kt = 1; kt < 8; ++kt) cm = fmaxf(cm, sacc[kt][r]);
            #pragma unroll
            for (int o = 8; o >= 1; o >>= 1) cm = fmaxf(cm, __shfl_xor(cm, o));
            if (lm == 0) redm[w * 16 + 4 * lg + r] = cm;
        }
        __syncthreads();   // barrier 1: redm complete
        // ---- global row max, exp -> P_lds, per-wave sums
        #pragma unroll
        for (int r = 0; r < 4; ++r) {
            int q = 4 * lg + r;
            float cm = redm[q];
            #pragma unroll
            for (int ww = 1; ww < 8; ++ww) cm = fmaxf(cm, redm[ww * 16 + q]);
            float fm = cm * scale;
            float sum = 0.f;
            #pragma unroll
            for (int kt = 0; kt < 8; ++kt) {
                float p = __expf(sacc[kt][r] * scale - fm);
                sum += p;
                int key = w * 128 + kt * 16 + lm;
                P_lds[(q * 1024 + key) ^ ((q & 7) << 3)] = __float2bfloat16(p);
            }
            #pragma unroll
            for (int o = 8; o >= 1; o >>= 1) sum += __shfl_xor(sum, o);
            if (lm == 0) reds[w * 16 + q] = sum;
        }
        __syncthreads();   // barrier 2: P_lds + reds complete
        float l_[4];
        #pragma unroll
        for (int r = 0; r < 4; ++r) {
            int q = 4 * lg + r;
            float csum = reds[q];
            #pragma unroll
            for (int ww = 1; ww < 8; ++ww) csum += reds[ww * 16 + q];
            l_[r] = csum;
        }
        // ---- PV over all 1024 keys; wave owns v = w*16 + lm
        f32x4 oacc = f32x4{0.f, 0.f, 0.f, 0.f};
        const __hip_bfloat16* xb0 = xT + (size_t)(b * LD + w * 16 + lm) * T_LEN;
        #pragma unroll
        for (int ks2 = 0; ks2 < 32; ++ks2) {
            bf16x8 pa = *(bf16x8*)&P_lds[(lm * 1024 + ks2 * 32 + 8 * lg) ^ ((lm & 7) << 3)];
            bf16x8 xb = *(const bf16x8*)(xb0 + ks2 * 32 + lg * 8);
            oacc = __builtin_amdgcn_mfma_f32_16x16x32_bf16(pa, xb, oacc, 0, 0, 0);
        }
        // ---- normalize -> att_lds (bf16, swizzled): rows q, col v = w*16+lm
        #pragma unroll
        for (int r = 0; r < 4; ++r) {
            int q = 4 * lg + r;
            att_lds[(q * 128 + w * 16 + lm) ^ ((q & 7) << 3)] = __float2bfloat16(oacc[r] / l_[r]);
        }
        __syncthreads();   // barrier 3: att_lds complete
        // ---- partial projection: wave owns j-tile [w*16, w*16+16)
        f32x4 cacc = f32x4{0.f, 0.f, 0.f, 0.f};
        #pragma unroll
        for (int ks = 0; ks < 4; ++ks) {
            bf16x8 aa = *(bf16x8*)&att_lds[(lm * 128 + ks * 32 + 8 * lg) ^ ((lm & 7) << 3)];
            bf16x8 wb = *(const bf16x8*)(WoT + (size_t)(w * 16 + lm) * HLD + h * LD + ks * 32 + lg * 8);
            cacc = __builtin_amdgcn_mfma_f32_16x16x32_bf16(aa, wb, cacc, 0, 0, 0);
        }
        #pragma unroll
        for (int r = 0; r < 4; ++r) {
            int q = q0 + 4 * lg + r;
            atomicAdd(&out[((size_t)b * NREF + q) * LD + w * 16 + lm], cacc[r]);
        }
    }
}

extern "C" void kernel_launch(void* const* d_in, const int* in_sizes, int n_in,
                              void* d_out, int out_size, void* d_ws, size_t ws_size,
                              hipStream_t stream) {
    const float* ts   = (const float*)d_in[0];
    const int*   ys0  = (const int*)d_in[1];
    const int*   ys1  = (const int*)d_in[2];
    const float* x    = (const float*)d_in[3];
    const float* emb0 = (const float*)d_in[4];
    const float* emb1 = (const float*)d_in[5];
    const float* Wq   = (const float*)d_in[6];
    const float* bq   = (const float*)d_in[7];
    const float* Wk   = (const float*)d_in[8];
    // d_in[9] = bk: cancels exactly in softmax (constant per (h,q) row) — unused
    const float* Wo   = (const float*)d_in[10];
    const float* bo   = (const float*)d_in[11];
    float* out = (float*)d_out;

    __hip_bfloat16* bfws = (__hip_bfloat16*)d_ws;
    __hip_bfloat16* A   = bfws;                 // 4*128*128      = 65536
    __hip_bfloat16* kin = A + 65536;            // 4096*128       = 524288
    __hip_bfloat16* xT  = kin + 524288;         // 4*128*1024     = 524288
    __hip_bfloat16* WoT = xT + 524288;          // 128*512        = 65536
    // total 1,179,648 bf16 = 2.25 MB

    void* args[] = {
        (void*)&ts, (void*)&ys0, (void*)&ys1, (void*)&x,
        (void*)&emb0, (void*)&emb1, (void*)&Wq, (void*)&bq,
        (void*)&Wk, (void*)&Wo, (void*)&bo,
        (void*)&A, (void*)&kin, (void*)&xT, (void*)&WoT, (void*)&out
    };
    hipLaunchCooperativeKernel((const void*)fused_all, dim3(128), dim3(512), args, 0, stream);
}